// Round 5
// baseline (714.014 us; speedup 1.0000x reference)
//
#include <hip/hip_runtime.h>
#include <stdint.h>

typedef __bf16 bf16;
typedef __bf16 bf16x8 __attribute__((ext_vector_type(8)));
typedef float floatx4 __attribute__((ext_vector_type(4)));
typedef unsigned short u16;

#define PDIM 16
#define EDIM 512
#define HDIM 512

__device__ __forceinline__ floatx4 mfma_16x16x32(bf16x8 a, bf16x8 b, floatx4 c) {
  return __builtin_amdgcn_mfma_f32_16x16x32_bf16(a, b, c, 0, 0, 0);
}

// ---- embedding fp32 -> bf16 (8 elems/thread) ----
__global__ __launch_bounds__(256) void kconv(const float* __restrict__ src,
                                             bf16* __restrict__ dst, int n8) {
  const int i = blockIdx.x * 256 + threadIdx.x;
  if (i >= n8) return;
  const float4* s = (const float4*)src;
  float4 a = s[i * 2], b = s[i * 2 + 1];
  bf16 o[8] = {(bf16)a.x, (bf16)a.y, (bf16)a.z, (bf16)a.w,
               (bf16)b.x, (bf16)b.y, (bf16)b.z, (bf16)b.w};
  *(uint4*)(dst + (size_t)i * 8) = *(uint4*)o;
}

// ---- biases + W2 fp32 -> bf16, packed [b0 | b1 | W2 | b2] ----
__global__ __launch_bounds__(256) void ksmall(const float* __restrict__ b0,
                                              const float* __restrict__ b1,
                                              const float* __restrict__ W2,
                                              const float* __restrict__ b2,
                                              bf16* __restrict__ dst) {
  const int j = blockIdx.x * 256 + threadIdx.x;
  if (j >= 24592) return;
  const float* src;
  int off;
  if (j < 8192)       { src = b0; off = j; }
  else if (j < 16384) { src = b1; off = j - 8192; }
  else if (j < 24576) { src = W2; off = j - 16384; }
  else                { src = b2; off = j - 24576; }
  dst[j] = (bf16)src[off];
}

// ---- weight transpose + cast: W[p][r][c] fp32 -> WT[p][c][r] bf16 ----
__global__ __launch_bounds__(256) void ktrans(const float* __restrict__ W0,
                                              const float* __restrict__ W1,
                                              bf16* __restrict__ W0T,
                                              bf16* __restrict__ W1T) {
  __shared__ u16 tile[64][72];  // pad 72 keeps 16B alignment of [r][s*8]
  const int b = blockIdx.x;
  const int m  = b >> 10;
  const int p  = (b >> 6) & 15;
  const int tr = (b >> 3) & 7;
  const int tc = b & 7;
  const float* src = (m ? W1 : W0) + ((size_t)p << 18);
  bf16*        dst = (m ? W1T : W0T) + ((size_t)p << 18);
  const int t = threadIdx.x;
#pragma unroll
  for (int i = 0; i < 2; ++i) {
    int c = t + i * 256;
    int r = c >> 3, s = c & 7;
    const float4* s32 =
        (const float4*)(src + (size_t)(tr * 64 + r) * 512 + tc * 64 + s * 8);
    float4 a = s32[0], bb = s32[1];
    bf16 o[8] = {(bf16)a.x, (bf16)a.y, (bf16)a.z, (bf16)a.w,
                 (bf16)bb.x, (bf16)bb.y, (bf16)bb.z, (bf16)bb.w};
    *(uint4*)&tile[r][s * 8] = *(uint4*)o;
  }
  __syncthreads();
#pragma unroll
  for (int i = 0; i < 2; ++i) {
    int c = t + i * 256;
    int r = c >> 3, s = c & 7;
    union { u16 u[8]; uint4 v; } tmp;
#pragma unroll
    for (int j = 0; j < 8; ++j) tmp.u[j] = tile[s * 8 + j][r];
    *(uint4*)(dst + (size_t)(tc * 64 + r) * 512 + tr * 64 + s * 8) = tmp.v;
  }
}

// ---- layer 0 (MFMA): h0[p][n][h] = relu(emb . W0T[p][h][:] + b0[p][h]) ----
// 128x128 tile, 4 waves, wave-tile 64x64 = 4x4 mfma 16x16x32 tiles.
__global__ __launch_bounds__(256) void kgemm1(const bf16* __restrict__ emb,
                                              const bf16* __restrict__ W0T,
                                              const bf16* __restrict__ small,
                                              bf16* __restrict__ h0,
                                              int Nc) {
  __shared__ bf16 Ab[2][128 * 32];
  __shared__ bf16 Bb[2][128 * 32];
  const int b  = blockIdx.x;
  const int p  = b & 15;
  const int ht = (b >> 4) & 3;
  const int nt = b >> 6;
  const int n0 = nt * 128;
  const int hc0 = ht * 128;
  const int tid = threadIdx.x;
  const int w = tid >> 6;
  const int lane = tid & 63;
  const int q = lane >> 4;
  const int mm = lane & 15;
  const int wr = (w >> 1) * 64;
  const int wc = (w & 1) * 64;
  const int srow = lane >> 2;       // 0..15 row within 16-row staging group
  const int kch  = (lane & 3) * 8;  // 16B chunk within 32-elem K-half

  const bf16* Wp = W0T + ((size_t)p << 18);
  const bf16* arow = emb + (size_t)n0 * 512;

  floatx4 acc[4][4];
#pragma unroll
  for (int i = 0; i < 4; ++i)
#pragma unroll
    for (int j = 0; j < 4; ++j) acc[i][j] = floatx4{0.f, 0.f, 0.f, 0.f};

  for (int k0 = 0; k0 < 512; k0 += 64) {
    uint4 ra[4], rb[4];
#pragma unroll
    for (int i = 0; i < 4; ++i) {
      const int half = i & 1;
      const int br = (w * 2 + (i >> 1)) * 16;
      ra[i] = *(const uint4*)(arow + (size_t)(br + srow) * 512 + k0 + half * 32 + kch);
      rb[i] = *(const uint4*)(Wp + (size_t)(hc0 + br + srow) * 512 + k0 + half * 32 + kch);
    }
    __syncthreads();
#pragma unroll
    for (int i = 0; i < 4; ++i) {
      const int half = i & 1;
      const int br = (w * 2 + (i >> 1)) * 16;
      ((uint4*)&Ab[half][br * 32])[lane] = ra[i];
      ((uint4*)&Bb[half][br * 32])[lane] = rb[i];
    }
    __syncthreads();
#pragma unroll
    for (int kk = 0; kk < 2; ++kk) {
      bf16x8 af[4], bv[4];
#pragma unroll
      for (int rt = 0; rt < 4; ++rt)
        af[rt] = *(const bf16x8*)&Ab[kk][(wr + rt * 16 + mm) * 32 + q * 8];
#pragma unroll
      for (int ct = 0; ct < 4; ++ct)
        bv[ct] = *(const bf16x8*)&Bb[kk][(wc + ct * 16 + mm) * 32 + q * 8];
#pragma unroll
      for (int rt = 0; rt < 4; ++rt)
#pragma unroll
        for (int ct = 0; ct < 4; ++ct)
          acc[rt][ct] = mfma_16x16x32(af[rt], bv[ct], acc[rt][ct]);
    }
  }

  // C/D layout: col=lane&15, row=(lane>>4)*4+reg (m89/m91)
#pragma unroll
  for (int ct = 0; ct < 4; ++ct) {
    const int hcol = hc0 + wc + ct * 16 + mm;
    const float bvv = (float)small[p * 512 + hcol];  // b0
#pragma unroll
    for (int rt = 0; rt < 4; ++rt) {
      const int nbase = n0 + wr + rt * 16 + q * 4;
#pragma unroll
      for (int r = 0; r < 4; ++r) {
        float v = acc[rt][ct][r] + bvv;
        v = v > 0.f ? v : 0.f;
        h0[((size_t)p * Nc + nbase + r) * 512 + hcol] = (bf16)v;
      }
    }
  }
}

// ---- layers 1+2+sigmoid fused (MFMA); h1 stays in registers ----
// block = (p, 64 rows), 4 waves, wave-tile 64x64; two 256-col strips.
__global__ __launch_bounds__(256) void kgemm2(const bf16* __restrict__ h0,
                                              const bf16* __restrict__ W1T,
                                              const bf16* __restrict__ small,
                                              float* __restrict__ out,
                                              int Nc) {
  __shared__ bf16 Ab[64 * 32];
  __shared__ bf16 Bb[256 * 32];
  __shared__ float oacc[64];
  const int b = blockIdx.x;
  const int p = b & 15;
  const int nt = b >> 4;
  const int n0 = nt * 64;
  const int tid = threadIdx.x;
  const int w = tid >> 6;
  const int lane = tid & 63;
  const int q = lane >> 4;
  const int mm = lane & 15;
  const int srow = lane >> 2;
  const int kch = (lane & 3) * 8;
  if (tid < 64) oacc[tid] = 0.f;

  const bf16* b1v_ = small + 8192 + p * 512;
  const bf16* W2v_ = small + 16384 + p * 512;
  const bf16* b2v_ = small + 24576;

  const bf16* Wp = W1T + ((size_t)p << 18);
  const bf16* Ap = h0 + ((size_t)p * Nc + n0) * 512;

  float pd[4][4];
#pragma unroll
  for (int i = 0; i < 4; ++i)
#pragma unroll
    for (int r = 0; r < 4; ++r) pd[i][r] = 0.f;

  for (int strip = 0; strip < 2; ++strip) {
    floatx4 acc[4][4];
#pragma unroll
    for (int i = 0; i < 4; ++i)
#pragma unroll
      for (int j = 0; j < 4; ++j) acc[i][j] = floatx4{0.f, 0.f, 0.f, 0.f};

    for (int kw = 0; kw < 512; kw += 32) {
      uint4 ra, rb[4];
      ra = *(const uint4*)(Ap + (size_t)(w * 16 + srow) * 512 + kw + kch);
#pragma unroll
      for (int i = 0; i < 4; ++i) {
        const int br = (w * 4 + i) * 16;
        rb[i] = *(const uint4*)(Wp + (size_t)(strip * 256 + br + srow) * 512 + kw + kch);
      }
      __syncthreads();
      ((uint4*)&Ab[w * 16 * 32])[lane] = ra;
#pragma unroll
      for (int i = 0; i < 4; ++i)
        ((uint4*)&Bb[(w * 4 + i) * 16 * 32])[lane] = rb[i];
      __syncthreads();
      bf16x8 af[4], bv[4];
#pragma unroll
      for (int rt = 0; rt < 4; ++rt)
        af[rt] = *(const bf16x8*)&Ab[(rt * 16 + mm) * 32 + q * 8];
#pragma unroll
      for (int ct = 0; ct < 4; ++ct)
        bv[ct] = *(const bf16x8*)&Bb[(w * 64 + ct * 16 + mm) * 32 + q * 8];
#pragma unroll
      for (int rt = 0; rt < 4; ++rt)
#pragma unroll
        for (int ct = 0; ct < 4; ++ct)
          acc[rt][ct] = mfma_16x16x32(af[rt], bv[ct], acc[rt][ct]);
    }
    // strip epilogue: h1 = relu(acc + b1); pd += h1 * w2
#pragma unroll
    for (int ct = 0; ct < 4; ++ct) {
      const int col = strip * 256 + w * 64 + ct * 16 + mm;
      const float b1v = (float)b1v_[col];
      const float w2v = (float)W2v_[col];
#pragma unroll
      for (int rt = 0; rt < 4; ++rt)
#pragma unroll
        for (int r = 0; r < 4; ++r) {
          float v = acc[rt][ct][r] + b1v;
          v = v > 0.f ? v : 0.f;
          pd[rt][r] += v * w2v;
        }
    }
  }
  // reduce over the 16 col-lanes of each row, accumulate in LDS
#pragma unroll
  for (int rt = 0; rt < 4; ++rt)
#pragma unroll
    for (int r = 0; r < 4; ++r) {
      float v = pd[rt][r];
      v += __shfl_xor(v, 1, 16);
      v += __shfl_xor(v, 2, 16);
      v += __shfl_xor(v, 4, 16);
      v += __shfl_xor(v, 8, 16);
      if (mm == 0) atomicAdd(&oacc[rt * 16 + q * 4 + r], v);
    }
  __syncthreads();
  if (tid < 64) {
    float v = oacc[tid] + (float)b2v_[p];
    v = 1.f / (1.f + expf(-v));
    out[(size_t)(n0 + tid) * 16 + p] = v;  // fp32 output
  }
}

// ---- fallback (tiny ws): slow but correct, fp32 in/out ----
__global__ __launch_bounds__(64) void knaive(const float* __restrict__ emb,
                                             const float* __restrict__ W0,
                                             const float* __restrict__ b0,
                                             const float* __restrict__ W1,
                                             const float* __restrict__ b1,
                                             const float* __restrict__ W2,
                                             const float* __restrict__ b2,
                                             float* __restrict__ out) {
  const int n = blockIdx.x >> 4;
  const int p = blockIdx.x & 15;
  __shared__ float h0s[512];
  __shared__ float h1s[512];
  const size_t wb = (size_t)p << 18;
  const int t = threadIdx.x;
  for (int h = t; h < 512; h += 64) {
    float a = 0.f;
    for (int e = 0; e < 512; ++e)
      a += emb[(size_t)n * 512 + e] * W0[wb + (size_t)e * 512 + h];
    a += b0[p * 512 + h];
    h0s[h] = a > 0.f ? a : 0.f;
  }
  __syncthreads();
  for (int k = t; k < 512; k += 64) {
    float a = 0.f;
    for (int hh = 0; hh < 512; ++hh)
      a += h0s[hh] * W1[wb + (size_t)hh * 512 + k];
    a += b1[p * 512 + k];
    h1s[k] = a > 0.f ? a : 0.f;
  }
  __syncthreads();
  float s = 0.f;
  for (int k = t; k < 512; k += 64) s += h1s[k] * W2[p * 512 + k];
  for (int off = 32; off; off >>= 1) s += __shfl_down(s, off, 64);
  if (t == 0)
    out[(size_t)n * 16 + p] = 1.f / (1.f + expf(-(s + b2[p])));
}

extern "C" void kernel_launch(void* const* d_in, const int* in_sizes, int n_in,
                              void* d_out, int out_size, void* d_ws, size_t ws_size,
                              hipStream_t stream) {
  (void)n_in; (void)out_size;
  const float* emb = (const float*)d_in[0];
  const float* W0  = (const float*)d_in[1];
  const float* b0  = (const float*)d_in[2];
  const float* W1  = (const float*)d_in[3];
  const float* b1  = (const float*)d_in[4];
  const float* W2  = (const float*)d_in[5];
  const float* b2  = (const float*)d_in[6];
  float* out = (float*)d_out;

  const int N = in_sizes[0] / 512;  // rows in e_embedding

  char* ws = (char*)d_ws;
  bf16* W0T    = (bf16*)ws;                                    // 8 MB
  bf16* W1T    = (bf16*)(ws + (8ll << 20));                    // 8 MB
  bf16* embB   = (bf16*)(ws + (16ll << 20));                   // N*1024 B
  bf16* smallB = (bf16*)(ws + (16ll << 20) + (size_t)N * 1024);  // 48 KB
  bf16* h0     = (bf16*)(ws + (16ll << 20) + (size_t)N * 1024 + 65536);
  const long long fixed = (16ll << 20) + (long long)N * 1024 + 65536;
  long long avail = (long long)ws_size - fixed;
  long long rows = avail > 0 ? avail / (16 * 512 * 2) : 0;
  int Nc = (int)((rows / 128) * 128);
  if (Nc > N) Nc = N;

  if (Nc < 128 || (N % 128) != 0) {  // ws too small or odd shape
    knaive<<<dim3(N * PDIM), dim3(64), 0, stream>>>(emb, W0, b0, W1, b1, W2,
                                                    b2, out);
    return;
  }

  kconv<<<dim3((N * 512 / 8 + 255) / 256), dim3(256), 0, stream>>>(
      emb, embB, N * 512 / 8);
  ksmall<<<dim3(97), dim3(256), 0, stream>>>(b0, b1, W2, b2, smallB);
  ktrans<<<dim3(2048), dim3(256), 0, stream>>>(W0, W1, W0T, W1T);

  for (int noff = 0; noff < N; noff += Nc) {
    const int cur = (N - noff < Nc) ? (N - noff) : Nc;  // multiple of 128
    kgemm1<<<dim3(64 * (cur / 128)), dim3(256), 0, stream>>>(
        embB + (size_t)noff * 512, W0T, smallB, h0, cur);
    kgemm2<<<dim3(16 * (cur / 64)), dim3(256), 0, stream>>>(
        h0, W1T, smallB, out + (size_t)noff * 16, cur);
  }
}

// Round 6
// 683.474 us; speedup vs baseline: 1.0447x; 1.0447x over previous
//
#include <hip/hip_runtime.h>
#include <stdint.h>

typedef __bf16 bf16;
typedef __bf16 bf16x8 __attribute__((ext_vector_type(8)));
typedef float floatx4 __attribute__((ext_vector_type(4)));
typedef unsigned short u16;

#define PDIM 16
#define EDIM 512
#define HDIM 512

__device__ __forceinline__ floatx4 mfma_16x16x32(bf16x8 a, bf16x8 b, floatx4 c) {
  return __builtin_amdgcn_mfma_f32_16x16x32_bf16(a, b, c, 0, 0, 0);
}

// ---- embedding fp32 -> bf16 (8 elems/thread) ----
__global__ __launch_bounds__(256) void kconv(const float* __restrict__ src,
                                             bf16* __restrict__ dst, int n8) {
  const int i = blockIdx.x * 256 + threadIdx.x;
  if (i >= n8) return;
  const float4* s = (const float4*)src;
  float4 a = s[i * 2], b = s[i * 2 + 1];
  bf16 o[8] = {(bf16)a.x, (bf16)a.y, (bf16)a.z, (bf16)a.w,
               (bf16)b.x, (bf16)b.y, (bf16)b.z, (bf16)b.w};
  *(uint4*)(dst + (size_t)i * 8) = *(uint4*)o;
}

// ---- biases + W2 fp32 -> bf16, packed [b0 | b1 | W2 | b2] ----
__global__ __launch_bounds__(256) void ksmall(const float* __restrict__ b0,
                                              const float* __restrict__ b1,
                                              const float* __restrict__ W2,
                                              const float* __restrict__ b2,
                                              bf16* __restrict__ dst) {
  const int j = blockIdx.x * 256 + threadIdx.x;
  if (j >= 24592) return;
  const float* src;
  int off;
  if (j < 8192)       { src = b0; off = j; }
  else if (j < 16384) { src = b1; off = j - 8192; }
  else if (j < 24576) { src = W2; off = j - 16384; }
  else                { src = b2; off = j - 24576; }
  dst[j] = (bf16)src[off];
}

// ---- weight transpose + cast: W[p][r][c] fp32 -> WT[p][c][r] bf16 ----
__global__ __launch_bounds__(256) void ktrans(const float* __restrict__ W0,
                                              const float* __restrict__ W1,
                                              bf16* __restrict__ W0T,
                                              bf16* __restrict__ W1T) {
  __shared__ u16 tile[64][72];
  const int b = blockIdx.x;
  const int m  = b >> 10;
  const int p  = (b >> 6) & 15;
  const int tr = (b >> 3) & 7;
  const int tc = b & 7;
  const float* src = (m ? W1 : W0) + ((size_t)p << 18);
  bf16*        dst = (m ? W1T : W0T) + ((size_t)p << 18);
  const int t = threadIdx.x;
#pragma unroll
  for (int i = 0; i < 2; ++i) {
    int c = t + i * 256;
    int r = c >> 3, s = c & 7;
    const float4* s32 =
        (const float4*)(src + (size_t)(tr * 64 + r) * 512 + tc * 64 + s * 8);
    float4 a = s32[0], bb = s32[1];
    bf16 o[8] = {(bf16)a.x, (bf16)a.y, (bf16)a.z, (bf16)a.w,
                 (bf16)bb.x, (bf16)bb.y, (bf16)bb.z, (bf16)bb.w};
    *(uint4*)&tile[r][s * 8] = *(uint4*)o;
  }
  __syncthreads();
#pragma unroll
  for (int i = 0; i < 2; ++i) {
    int c = t + i * 256;
    int r = c >> 3, s = c & 7;
    union { u16 u[8]; uint4 v; } tmp;
#pragma unroll
    for (int j = 0; j < 8; ++j) tmp.u[j] = tile[s * 8 + j][r];
    *(uint4*)(dst + (size_t)(tc * 64 + r) * 512 + tr * 64 + s * 8) = tmp.v;
  }
}

// ---- layer 0 (MFMA, pipelined): h0 = relu(emb . W0T^T + b0), bf16 out ----
// 128x128 tile, 4 waves, wave-tile 64x64, BK=64. Register prefetch of tile
// k+1 is issued after the compute barrier so the vmcnt wait lands at the
// NEXT iteration's LDS store, overlapping global latency with the 32 MFMAs.
__global__ __launch_bounds__(256) void kgemm1(const bf16* __restrict__ emb,
                                              const bf16* __restrict__ W0T,
                                              const bf16* __restrict__ small,
                                              bf16* __restrict__ h0,
                                              int Nc) {
  __shared__ bf16 Ab[2][128 * 32];
  __shared__ bf16 Bb[2][128 * 32];
  const int b  = blockIdx.x;
  const int p  = b & 15;
  const int ht = (b >> 4) & 3;
  const int nt = b >> 6;
  const int n0 = nt * 128;
  const int hc0 = ht * 128;
  const int tid = threadIdx.x;
  const int w = tid >> 6;
  const int lane = tid & 63;
  const int q = lane >> 4;
  const int mm = lane & 15;
  const int wr = (w >> 1) * 64;
  const int wc = (w & 1) * 64;
  const int srow = lane >> 2;
  const int kch  = (lane & 3) * 8;

  const bf16* Arow = emb + (size_t)n0 * 512;
  const bf16* Brow = W0T + ((size_t)p << 18) + (size_t)hc0 * 512;

  floatx4 acc[4][4];
#pragma unroll
  for (int i = 0; i < 4; ++i)
#pragma unroll
    for (int j = 0; j < 4; ++j) acc[i][j] = floatx4{0.f, 0.f, 0.f, 0.f};

  uint4 ra[4], rb[4];
#pragma unroll
  for (int i = 0; i < 4; ++i) {
    const int half = i & 1;
    const int br = (w * 2 + (i >> 1)) * 16;
    ra[i] = *(const uint4*)(Arow + (size_t)(br + srow) * 512 + half * 32 + kch);
    rb[i] = *(const uint4*)(Brow + (size_t)(br + srow) * 512 + half * 32 + kch);
  }

  for (int k0 = 0; k0 < 512; k0 += 64) {
    __syncthreads();
#pragma unroll
    for (int i = 0; i < 4; ++i) {
      const int half = i & 1;
      const int br = (w * 2 + (i >> 1)) * 16;
      ((uint4*)&Ab[half][br * 32])[lane] = ra[i];
      ((uint4*)&Bb[half][br * 32])[lane] = rb[i];
    }
    __syncthreads();
    if (k0 + 64 < 512) {
      const int kn = k0 + 64;
#pragma unroll
      for (int i = 0; i < 4; ++i) {
        const int half = i & 1;
        const int br = (w * 2 + (i >> 1)) * 16;
        ra[i] = *(const uint4*)(Arow + (size_t)(br + srow) * 512 + kn + half * 32 + kch);
        rb[i] = *(const uint4*)(Brow + (size_t)(br + srow) * 512 + kn + half * 32 + kch);
      }
    }
#pragma unroll
    for (int kk = 0; kk < 2; ++kk) {
      bf16x8 af[4], bv[4];
#pragma unroll
      for (int rt = 0; rt < 4; ++rt)
        af[rt] = *(const bf16x8*)&Ab[kk][(wr + rt * 16 + mm) * 32 + q * 8];
#pragma unroll
      for (int ct = 0; ct < 4; ++ct)
        bv[ct] = *(const bf16x8*)&Bb[kk][(wc + ct * 16 + mm) * 32 + q * 8];
#pragma unroll
      for (int rt = 0; rt < 4; ++rt)
#pragma unroll
        for (int ct = 0; ct < 4; ++ct)
          acc[rt][ct] = mfma_16x16x32(af[rt], bv[ct], acc[rt][ct]);
    }
  }

  // C/D layout: col=lane&15, row=(lane>>4)*4+reg
#pragma unroll
  for (int ct = 0; ct < 4; ++ct) {
    const int hcol = hc0 + wc + ct * 16 + mm;
    const float bvv = (float)small[p * 512 + hcol];  // b0
#pragma unroll
    for (int rt = 0; rt < 4; ++rt) {
      const int nbase = n0 + wr + rt * 16 + q * 4;
#pragma unroll
      for (int r = 0; r < 4; ++r) {
        float v = acc[rt][ct][r] + bvv;
        v = v > 0.f ? v : 0.f;
        h0[((size_t)p * Nc + nbase + r) * 512 + hcol] = (bf16)v;
      }
    }
  }
}

// ---- layer 1 GEMM + fused partial layer-2 dot (pipelined, 128x128) ----
// Same GEMM structure as kgemm1. Epilogue: h1=relu(acc+b1) stays in regs,
// pd[row] += h1*W2[col]; reduced over the 16 col-lanes and the block's 128
// cols into pacc[(p*4+ht)][n]. kfin sums the 4 ht partials + sigmoid.
__global__ __launch_bounds__(256) void kgemm2(const bf16* __restrict__ h0,
                                              const bf16* __restrict__ W1T,
                                              const bf16* __restrict__ small,
                                              float* __restrict__ pacc,
                                              int Nc) {
  __shared__ bf16 Ab[2][128 * 32];
  __shared__ bf16 Bb[2][128 * 32];
  __shared__ float oacc[128];
  const int b  = blockIdx.x;
  const int p  = b & 15;
  const int ht = (b >> 4) & 3;
  const int nt = b >> 6;
  const int n0 = nt * 128;
  const int hc0 = ht * 128;
  const int tid = threadIdx.x;
  const int w = tid >> 6;
  const int lane = tid & 63;
  const int q = lane >> 4;
  const int mm = lane & 15;
  const int wr = (w >> 1) * 64;
  const int wc = (w & 1) * 64;
  const int srow = lane >> 2;
  const int kch  = (lane & 3) * 8;
  if (tid < 128) oacc[tid] = 0.f;

  const bf16* Arow = h0 + ((size_t)p * Nc + n0) * 512;
  const bf16* Brow = W1T + ((size_t)p << 18) + (size_t)hc0 * 512;

  floatx4 acc[4][4];
#pragma unroll
  for (int i = 0; i < 4; ++i)
#pragma unroll
    for (int j = 0; j < 4; ++j) acc[i][j] = floatx4{0.f, 0.f, 0.f, 0.f};

  uint4 ra[4], rb[4];
#pragma unroll
  for (int i = 0; i < 4; ++i) {
    const int half = i & 1;
    const int br = (w * 2 + (i >> 1)) * 16;
    ra[i] = *(const uint4*)(Arow + (size_t)(br + srow) * 512 + half * 32 + kch);
    rb[i] = *(const uint4*)(Brow + (size_t)(br + srow) * 512 + half * 32 + kch);
  }

  for (int k0 = 0; k0 < 512; k0 += 64) {
    __syncthreads();
#pragma unroll
    for (int i = 0; i < 4; ++i) {
      const int half = i & 1;
      const int br = (w * 2 + (i >> 1)) * 16;
      ((uint4*)&Ab[half][br * 32])[lane] = ra[i];
      ((uint4*)&Bb[half][br * 32])[lane] = rb[i];
    }
    __syncthreads();
    if (k0 + 64 < 512) {
      const int kn = k0 + 64;
#pragma unroll
      for (int i = 0; i < 4; ++i) {
        const int half = i & 1;
        const int br = (w * 2 + (i >> 1)) * 16;
        ra[i] = *(const uint4*)(Arow + (size_t)(br + srow) * 512 + kn + half * 32 + kch);
        rb[i] = *(const uint4*)(Brow + (size_t)(br + srow) * 512 + kn + half * 32 + kch);
      }
    }
#pragma unroll
    for (int kk = 0; kk < 2; ++kk) {
      bf16x8 af[4], bv[4];
#pragma unroll
      for (int rt = 0; rt < 4; ++rt)
        af[rt] = *(const bf16x8*)&Ab[kk][(wr + rt * 16 + mm) * 32 + q * 8];
#pragma unroll
      for (int ct = 0; ct < 4; ++ct)
        bv[ct] = *(const bf16x8*)&Bb[kk][(wc + ct * 16 + mm) * 32 + q * 8];
#pragma unroll
      for (int rt = 0; rt < 4; ++rt)
#pragma unroll
        for (int ct = 0; ct < 4; ++ct)
          acc[rt][ct] = mfma_16x16x32(af[rt], bv[ct], acc[rt][ct]);
    }
  }

  // epilogue: h1 = relu(acc + b1); per-row partial dot with W2
  const bf16* b1v_ = small + 8192 + p * 512;
  const bf16* W2v_ = small + 16384 + p * 512;
  float pd[4][4];
#pragma unroll
  for (int i = 0; i < 4; ++i)
#pragma unroll
    for (int r = 0; r < 4; ++r) pd[i][r] = 0.f;
#pragma unroll
  for (int ct = 0; ct < 4; ++ct) {
    const int col = hc0 + wc + ct * 16 + mm;
    const float b1v = (float)b1v_[col - hc0 + hc0];  // = b1v_[col]
    const float w2v = (float)W2v_[col - hc0 + hc0];
#pragma unroll
    for (int rt = 0; rt < 4; ++rt)
#pragma unroll
      for (int r = 0; r < 4; ++r) {
        float v = acc[rt][ct][r] + b1v;
        v = v > 0.f ? v : 0.f;
        pd[rt][r] += v * w2v;
      }
  }
#pragma unroll
  for (int rt = 0; rt < 4; ++rt)
#pragma unroll
    for (int r = 0; r < 4; ++r) {
      float v = pd[rt][r];
      v += __shfl_xor(v, 1, 16);
      v += __shfl_xor(v, 2, 16);
      v += __shfl_xor(v, 4, 16);
      v += __shfl_xor(v, 8, 16);
      if (mm == 0) atomicAdd(&oacc[wr + rt * 16 + q * 4 + r], v);
    }
  __syncthreads();
  if (tid < 128)
    pacc[(size_t)(p * 4 + ht) * Nc + n0 + tid] = oacc[tid];
}

// ---- finish: sum 4 ht partials + b2, sigmoid, fp32 out ----
__global__ __launch_bounds__(256) void kfin(const float* __restrict__ pacc,
                                            const bf16* __restrict__ small,
                                            float* __restrict__ out, int Nc) {
  const int idx = blockIdx.x * 256 + threadIdx.x;
  if (idx >= Nc * 16) return;
  const int n = idx >> 4;
  const int p = idx & 15;
  float v = (float)small[24576 + p];
#pragma unroll
  for (int ht = 0; ht < 4; ++ht) v += pacc[(size_t)(p * 4 + ht) * Nc + n];
  out[(size_t)n * 16 + p] = 1.f / (1.f + expf(-v));
}

// ---- fallback (tiny ws): slow but correct, fp32 in/out ----
__global__ __launch_bounds__(64) void knaive(const float* __restrict__ emb,
                                             const float* __restrict__ W0,
                                             const float* __restrict__ b0,
                                             const float* __restrict__ W1,
                                             const float* __restrict__ b1,
                                             const float* __restrict__ W2,
                                             const float* __restrict__ b2,
                                             float* __restrict__ out) {
  const int n = blockIdx.x >> 4;
  const int p = blockIdx.x & 15;
  __shared__ float h0s[512];
  __shared__ float h1s[512];
  const size_t wb = (size_t)p << 18;
  const int t = threadIdx.x;
  for (int h = t; h < 512; h += 64) {
    float a = 0.f;
    for (int e = 0; e < 512; ++e)
      a += emb[(size_t)n * 512 + e] * W0[wb + (size_t)e * 512 + h];
    a += b0[p * 512 + h];
    h0s[h] = a > 0.f ? a : 0.f;
  }
  __syncthreads();
  for (int k = t; k < 512; k += 64) {
    float a = 0.f;
    for (int hh = 0; hh < 512; ++hh)
      a += h0s[hh] * W1[wb + (size_t)hh * 512 + k];
    a += b1[p * 512 + k];
    h1s[k] = a > 0.f ? a : 0.f;
  }
  __syncthreads();
  float s = 0.f;
  for (int k = t; k < 512; k += 64) s += h1s[k] * W2[p * 512 + k];
  for (int off = 32; off; off >>= 1) s += __shfl_down(s, off, 64);
  if (t == 0)
    out[(size_t)n * 16 + p] = 1.f / (1.f + expf(-(s + b2[p])));
}

extern "C" void kernel_launch(void* const* d_in, const int* in_sizes, int n_in,
                              void* d_out, int out_size, void* d_ws, size_t ws_size,
                              hipStream_t stream) {
  (void)n_in; (void)out_size;
  const float* emb = (const float*)d_in[0];
  const float* W0  = (const float*)d_in[1];
  const float* b0  = (const float*)d_in[2];
  const float* W1  = (const float*)d_in[3];
  const float* b1  = (const float*)d_in[4];
  const float* W2  = (const float*)d_in[5];
  const float* b2  = (const float*)d_in[6];
  float* out = (float*)d_out;

  const int N = in_sizes[0] / 512;  // rows in e_embedding

  char* ws = (char*)d_ws;
  bf16*  W0T    = (bf16*)ws;                                 // 8 MB
  bf16*  W1T    = (bf16*)(ws + (8ll << 20));                 // 8 MB
  bf16*  smallB = (bf16*)(ws + (16ll << 20));                // 64 KB
  float* pacc   = (float*)(ws + (16ll << 20) + 65536);       // 256*N B
  bf16*  embB   = (bf16*)(ws + (16ll << 20) + 65536 + (size_t)N * 256);
  bf16*  h0     = (bf16*)(ws + (16ll << 20) + 65536 + (size_t)N * 256 +
                          (size_t)N * 1024);
  const long long fixed = (16ll << 20) + 65536 + (long long)N * 256 +
                          (long long)N * 1024;
  long long avail = (long long)ws_size - fixed;
  long long rows = avail > 0 ? avail / (16 * 512 * 2) : 0;
  int Nc = (int)((rows / 128) * 128);
  if (Nc > N) Nc = N;

  if (Nc < 128 || (N % 128) != 0) {
    knaive<<<dim3(N * PDIM), dim3(64), 0, stream>>>(emb, W0, b0, W1, b1, W2,
                                                    b2, out);
    return;
  }

  kconv<<<dim3((N * 512 / 8 + 255) / 256), dim3(256), 0, stream>>>(
      emb, embB, N * 512 / 8);
  ksmall<<<dim3(97), dim3(256), 0, stream>>>(b0, b1, W2, b2, smallB);
  ktrans<<<dim3(2048), dim3(256), 0, stream>>>(W0, W1, W0T, W1T);

  for (int noff = 0; noff < N; noff += Nc) {
    const int cur = (N - noff < Nc) ? (N - noff) : Nc;  // multiple of 128
    kgemm1<<<dim3(64 * (cur / 128)), dim3(256), 0, stream>>>(
        embB + (size_t)noff * 512, W0T, smallB, h0, cur);
    kgemm2<<<dim3(64 * (cur / 128)), dim3(256), 0, stream>>>(
        h0, W1T, smallB, pacc, cur);
    kfin<<<dim3((cur * 16 + 255) / 256), dim3(256), 0, stream>>>(
        pacc, smallB, out + (size_t)noff * 16, cur);
  }
}

// Round 7
// 305.387 us; speedup vs baseline: 2.3381x; 2.2381x over previous
//
#include <hip/hip_runtime.h>
#include <stdint.h>

typedef __bf16 bf16;
typedef __bf16 bf16x8 __attribute__((ext_vector_type(8)));
typedef float floatx4 __attribute__((ext_vector_type(4)));
typedef unsigned short u16;

#define PDIM 16
#define EDIM 512
#define HDIM 512

__device__ __forceinline__ floatx4 mfma_16x16x32(bf16x8 a, bf16x8 b, floatx4 c) {
  return __builtin_amdgcn_mfma_f32_16x16x32_bf16(a, b, c, 0, 0, 0);
}

// async 16B/lane global->LDS. LDS dest = wave-uniform base + lane*16 (m97).
// NOTE: direct addrspacecast, NOT integer truncation (R1's bug).
__device__ __forceinline__ void stage16(const bf16* g, bf16* lds_base) {
  __builtin_amdgcn_global_load_lds(
      (const __attribute__((address_space(1))) void*)g,
      (__attribute__((address_space(3))) void*)lds_base, 16, 0, 0);
}

// ---- embedding fp32 -> bf16 (8 elems/thread) ----
__global__ __launch_bounds__(256) void kconv(const float* __restrict__ src,
                                             bf16* __restrict__ dst, int n8) {
  const int i = blockIdx.x * 256 + threadIdx.x;
  if (i >= n8) return;
  const float4* s = (const float4*)src;
  float4 a = s[i * 2], b = s[i * 2 + 1];
  bf16 o[8] = {(bf16)a.x, (bf16)a.y, (bf16)a.z, (bf16)a.w,
               (bf16)b.x, (bf16)b.y, (bf16)b.z, (bf16)b.w};
  *(uint4*)(dst + (size_t)i * 8) = *(uint4*)o;
}

// ---- biases + W2 fp32 -> bf16, packed [b0 | b1 | W2 | b2] ----
__global__ __launch_bounds__(256) void ksmall(const float* __restrict__ b0,
                                              const float* __restrict__ b1,
                                              const float* __restrict__ W2,
                                              const float* __restrict__ b2,
                                              bf16* __restrict__ dst) {
  const int j = blockIdx.x * 256 + threadIdx.x;
  if (j >= 24592) return;
  const float* src;
  int off;
  if (j < 8192)       { src = b0; off = j; }
  else if (j < 16384) { src = b1; off = j - 8192; }
  else if (j < 24576) { src = W2; off = j - 16384; }
  else                { src = b2; off = j - 24576; }
  dst[j] = (bf16)src[off];
}

// ---- weight transpose + cast: W[p][r][c] fp32 -> WT[p][c][r] bf16 ----
__global__ __launch_bounds__(256) void ktrans(const float* __restrict__ W0,
                                              const float* __restrict__ W1,
                                              bf16* __restrict__ W0T,
                                              bf16* __restrict__ W1T) {
  __shared__ u16 tile[64][72];
  const int b = blockIdx.x;
  const int m  = b >> 10;
  const int p  = (b >> 6) & 15;
  const int tr = (b >> 3) & 7;
  const int tc = b & 7;
  const float* src = (m ? W1 : W0) + ((size_t)p << 18);
  bf16*        dst = (m ? W1T : W0T) + ((size_t)p << 18);
  const int t = threadIdx.x;
#pragma unroll
  for (int i = 0; i < 2; ++i) {
    int c = t + i * 256;
    int r = c >> 3, s = c & 7;
    const float4* s32 =
        (const float4*)(src + (size_t)(tr * 64 + r) * 512 + tc * 64 + s * 8);
    float4 a = s32[0], bb = s32[1];
    bf16 o[8] = {(bf16)a.x, (bf16)a.y, (bf16)a.z, (bf16)a.w,
                 (bf16)bb.x, (bf16)bb.y, (bf16)bb.z, (bf16)bb.w};
    *(uint4*)&tile[r][s * 8] = *(uint4*)o;
  }
  __syncthreads();
#pragma unroll
  for (int i = 0; i < 2; ++i) {
    int c = t + i * 256;
    int r = c >> 3, s = c & 7;
    union { u16 u[8]; uint4 v; } tmp;
#pragma unroll
    for (int j = 0; j < 8; ++j) tmp.u[j] = tile[s * 8 + j][r];
    *(uint4*)(dst + (size_t)(tc * 64 + r) * 512 + tr * 64 + s * 8) = tmp.v;
  }
}

// ---- layer 0: h0 = relu(emb . W0T^T + b0), bf16; async-staged K-loop,
// LDS-staged coalesced epilogue (C round-trips through the dead A/B tiles).
__global__ __launch_bounds__(256) void kgemm1(const bf16* __restrict__ emb,
                                              const bf16* __restrict__ W0T,
                                              const bf16* __restrict__ small,
                                              bf16* __restrict__ h0,
                                              int Nc) {
  __shared__ bf16 smem[16384];  // [Ab 2x4096 | Bb 2x4096]; epilogue: C 64x136
  bf16* Ab = smem;
  bf16* Bb = smem + 8192;
  const int b  = blockIdx.x;
  const int p  = b & 15;
  const int ht = (b >> 4) & 3;
  const int nt = b >> 6;
  const int n0 = nt * 128;
  const int hc0 = ht * 128;
  const int tid = threadIdx.x;
  const int w = tid >> 6;
  const int lane = tid & 63;
  const int q = lane >> 4;
  const int mm = lane & 15;
  const int wr = (w >> 1) * 64;
  const int wc = (w & 1) * 64;
  const int srow = lane >> 2;

  const bf16* Arow = emb + (size_t)n0 * 512;
  const bf16* Brow = W0T + ((size_t)p << 18) + (size_t)hc0 * 512;

  floatx4 acc[4][4];
#pragma unroll
  for (int i = 0; i < 4; ++i)
#pragma unroll
    for (int j = 0; j < 4; ++j) acc[i][j] = floatx4{0.f, 0.f, 0.f, 0.f};

  const int kch = (lane & 3) * 8;
  for (int k0 = 0; k0 < 512; k0 += 64) {
    __syncthreads();  // previous tiles fully consumed
#pragma unroll
    for (int i = 0; i < 4; ++i) {
      const int half = i & 1;
      const int br = (w * 2 + (i >> 1)) * 16;
      stage16(Arow + (size_t)(br + srow) * 512 + k0 + half * 32 + kch,
              Ab + half * 4096 + br * 32);
      stage16(Brow + (size_t)(br + srow) * 512 + k0 + half * 32 + kch,
              Bb + half * 4096 + br * 32);
    }
    __syncthreads();  // drains vmcnt -> tiles landed
#pragma unroll
    for (int kk = 0; kk < 2; ++kk) {
      bf16x8 af[4], bv[4];
#pragma unroll
      for (int rt = 0; rt < 4; ++rt)
        af[rt] = *(const bf16x8*)&Ab[kk * 4096 + (wr + rt * 16 + mm) * 32 + q * 8];
#pragma unroll
      for (int ct = 0; ct < 4; ++ct)
        bv[ct] = *(const bf16x8*)&Bb[kk * 4096 + (wc + ct * 16 + mm) * 32 + q * 8];
#pragma unroll
      for (int rt = 0; rt < 4; ++rt)
#pragma unroll
        for (int ct = 0; ct < 4; ++ct)
          acc[rt][ct] = mfma_16x16x32(af[rt], bv[ct], acc[rt][ct]);
    }
  }

  // --- coalesced epilogue: two 64-row passes through LDS (stride 136) ---
  __syncthreads();  // all fragment reads done; smem reusable
  bf16* Cst = smem;  // 64 x 136 = 8704 elems
#pragma unroll
  for (int pass = 0; pass < 2; ++pass) {
    if ((w >> 1) == pass) {  // waves whose wr matches this row-half
#pragma unroll
      for (int ct = 0; ct < 4; ++ct) {
        const float bvv = (float)small[p * 512 + hc0 + wc + ct * 16 + mm];
#pragma unroll
        for (int rt = 0; rt < 4; ++rt)
#pragma unroll
          for (int r = 0; r < 4; ++r) {
            float v = acc[rt][ct][r] + bvv;
            v = v > 0.f ? v : 0.f;
            Cst[(rt * 16 + q * 4 + r) * 136 + wc + ct * 16 + mm] = (bf16)v;
          }
      }
    }
    __syncthreads();
#pragma unroll
    for (int i = 0; i < 4; ++i) {
      const int row = (tid >> 4) + i * 16;  // 0..63
      const int chunk = tid & 15;           // 16B chunk of the 128-col slice
      uint4 v = *(const uint4*)&Cst[row * 136 + chunk * 8];
      *(uint4*)&h0[((size_t)p * Nc + n0 + pass * 64 + row) * 512 + hc0 +
                   chunk * 8] = v;
    }
    if (pass == 0) __syncthreads();
  }
}

// ---- layer 1 GEMM + fused partial layer-2 dot (async-staged) ----
__global__ __launch_bounds__(256) void kgemm2(const bf16* __restrict__ h0,
                                              const bf16* __restrict__ W1T,
                                              const bf16* __restrict__ small,
                                              float* __restrict__ pacc,
                                              int Nc) {
  __shared__ bf16 smem[16384];
  __shared__ float oacc[128];
  bf16* Ab = smem;
  bf16* Bb = smem + 8192;
  const int b  = blockIdx.x;
  const int p  = b & 15;
  const int ht = (b >> 4) & 3;
  const int nt = b >> 6;
  const int n0 = nt * 128;
  const int hc0 = ht * 128;
  const int tid = threadIdx.x;
  const int w = tid >> 6;
  const int lane = tid & 63;
  const int q = lane >> 4;
  const int mm = lane & 15;
  const int wr = (w >> 1) * 64;
  const int wc = (w & 1) * 64;
  const int srow = lane >> 2;
  const int kch = (lane & 3) * 8;
  if (tid < 128) oacc[tid] = 0.f;

  const bf16* Arow = h0 + ((size_t)p * Nc + n0) * 512;
  const bf16* Brow = W1T + ((size_t)p << 18) + (size_t)hc0 * 512;

  floatx4 acc[4][4];
#pragma unroll
  for (int i = 0; i < 4; ++i)
#pragma unroll
    for (int j = 0; j < 4; ++j) acc[i][j] = floatx4{0.f, 0.f, 0.f, 0.f};

  for (int k0 = 0; k0 < 512; k0 += 64) {
    __syncthreads();
#pragma unroll
    for (int i = 0; i < 4; ++i) {
      const int half = i & 1;
      const int br = (w * 2 + (i >> 1)) * 16;
      stage16(Arow + (size_t)(br + srow) * 512 + k0 + half * 32 + kch,
              Ab + half * 4096 + br * 32);
      stage16(Brow + (size_t)(br + srow) * 512 + k0 + half * 32 + kch,
              Bb + half * 4096 + br * 32);
    }
    __syncthreads();
#pragma unroll
    for (int kk = 0; kk < 2; ++kk) {
      bf16x8 af[4], bv[4];
#pragma unroll
      for (int rt = 0; rt < 4; ++rt)
        af[rt] = *(const bf16x8*)&Ab[kk * 4096 + (wr + rt * 16 + mm) * 32 + q * 8];
#pragma unroll
      for (int ct = 0; ct < 4; ++ct)
        bv[ct] = *(const bf16x8*)&Bb[kk * 4096 + (wc + ct * 16 + mm) * 32 + q * 8];
#pragma unroll
      for (int rt = 0; rt < 4; ++rt)
#pragma unroll
        for (int ct = 0; ct < 4; ++ct)
          acc[rt][ct] = mfma_16x16x32(af[rt], bv[ct], acc[rt][ct]);
    }
  }

  // epilogue: h1 = relu(acc + b1); per-row partial dot with W2
  const bf16* b1v_ = small + 8192 + p * 512;
  const bf16* W2v_ = small + 16384 + p * 512;
  float pd[4][4];
#pragma unroll
  for (int i = 0; i < 4; ++i)
#pragma unroll
    for (int r = 0; r < 4; ++r) pd[i][r] = 0.f;
#pragma unroll
  for (int ct = 0; ct < 4; ++ct) {
    const int col = hc0 + wc + ct * 16 + mm;
    const float b1v = (float)b1v_[col];
    const float w2v = (float)W2v_[col];
#pragma unroll
    for (int rt = 0; rt < 4; ++rt)
#pragma unroll
      for (int r = 0; r < 4; ++r) {
        float v = acc[rt][ct][r] + b1v;
        v = v > 0.f ? v : 0.f;
        pd[rt][r] += v * w2v;
      }
  }
#pragma unroll
  for (int rt = 0; rt < 4; ++rt)
#pragma unroll
    for (int r = 0; r < 4; ++r) {
      float v = pd[rt][r];
      v += __shfl_xor(v, 1, 16);
      v += __shfl_xor(v, 2, 16);
      v += __shfl_xor(v, 4, 16);
      v += __shfl_xor(v, 8, 16);
      if (mm == 0) atomicAdd(&oacc[wr + rt * 16 + q * 4 + r], v);
    }
  __syncthreads();
  if (tid < 128)
    pacc[(size_t)(p * 4 + ht) * Nc + n0 + tid] = oacc[tid];
}

// ---- finish: sum 4 ht partials + b2, sigmoid, fp32 out ----
__global__ __launch_bounds__(256) void kfin(const float* __restrict__ pacc,
                                            const bf16* __restrict__ small,
                                            float* __restrict__ out, int Nc) {
  const int idx = blockIdx.x * 256 + threadIdx.x;
  if (idx >= Nc * 16) return;
  const int n = idx >> 4;
  const int p = idx & 15;
  float v = (float)small[24576 + p];
#pragma unroll
  for (int ht = 0; ht < 4; ++ht) v += pacc[(size_t)(p * 4 + ht) * Nc + n];
  out[(size_t)n * 16 + p] = 1.f / (1.f + expf(-v));
}

// ---- fallback (tiny ws): slow but correct, fp32 in/out ----
__global__ __launch_bounds__(64) void knaive(const float* __restrict__ emb,
                                             const float* __restrict__ W0,
                                             const float* __restrict__ b0,
                                             const float* __restrict__ W1,
                                             const float* __restrict__ b1,
                                             const float* __restrict__ W2,
                                             const float* __restrict__ b2,
                                             float* __restrict__ out) {
  const int n = blockIdx.x >> 4;
  const int p = blockIdx.x & 15;
  __shared__ float h0s[512];
  __shared__ float h1s[512];
  const size_t wb = (size_t)p << 18;
  const int t = threadIdx.x;
  for (int h = t; h < 512; h += 64) {
    float a = 0.f;
    for (int e = 0; e < 512; ++e)
      a += emb[(size_t)n * 512 + e] * W0[wb + (size_t)e * 512 + h];
    a += b0[p * 512 + h];
    h0s[h] = a > 0.f ? a : 0.f;
  }
  __syncthreads();
  for (int k = t; k < 512; k += 64) {
    float a = 0.f;
    for (int hh = 0; hh < 512; ++hh)
      a += h0s[hh] * W1[wb + (size_t)hh * 512 + k];
    a += b1[p * 512 + k];
    h1s[k] = a > 0.f ? a : 0.f;
  }
  __syncthreads();
  float s = 0.f;
  for (int k = t; k < 512; k += 64) s += h1s[k] * W2[p * 512 + k];
  for (int off = 32; off; off >>= 1) s += __shfl_down(s, off, 64);
  if (t == 0)
    out[(size_t)n * 16 + p] = 1.f / (1.f + expf(-(s + b2[p])));
}

extern "C" void kernel_launch(void* const* d_in, const int* in_sizes, int n_in,
                              void* d_out, int out_size, void* d_ws, size_t ws_size,
                              hipStream_t stream) {
  (void)n_in; (void)out_size;
  const float* emb = (const float*)d_in[0];
  const float* W0  = (const float*)d_in[1];
  const float* b0  = (const float*)d_in[2];
  const float* W1  = (const float*)d_in[3];
  const float* b1  = (const float*)d_in[4];
  const float* W2  = (const float*)d_in[5];
  const float* b2  = (const float*)d_in[6];
  float* out = (float*)d_out;

  const int N = in_sizes[0] / 512;  // rows in e_embedding

  char* ws = (char*)d_ws;
  bf16*  W0T    = (bf16*)ws;                                 // 8 MB
  bf16*  W1T    = (bf16*)(ws + (8ll << 20));                 // 8 MB
  bf16*  smallB = (bf16*)(ws + (16ll << 20));                // 64 KB
  float* pacc   = (float*)(ws + (16ll << 20) + 65536);       // 256*N B
  bf16*  embB   = (bf16*)(ws + (16ll << 20) + 65536 + (size_t)N * 256);
  bf16*  h0     = (bf16*)(ws + (16ll << 20) + 65536 + (size_t)N * 256 +
                          (size_t)N * 1024);
  const long long fixed = (16ll << 20) + 65536 + (long long)N * 256 +
                          (long long)N * 1024;
  long long avail = (long long)ws_size - fixed;
  long long rows = avail > 0 ? avail / (16 * 512 * 2) : 0;
  int Nc = (int)((rows / 128) * 128);
  if (Nc > N) Nc = N;

  if (Nc < 128 || (N % 128) != 0) {
    knaive<<<dim3(N * PDIM), dim3(64), 0, stream>>>(emb, W0, b0, W1, b1, W2,
                                                    b2, out);
    return;
  }

  kconv<<<dim3((N * 512 / 8 + 255) / 256), dim3(256), 0, stream>>>(
      emb, embB, N * 512 / 8);
  ksmall<<<dim3(97), dim3(256), 0, stream>>>(b0, b1, W2, b2, smallB);
  ktrans<<<dim3(2048), dim3(256), 0, stream>>>(W0, W1, W0T, W1T);

  for (int noff = 0; noff < N; noff += Nc) {
    const int cur = (N - noff < Nc) ? (N - noff) : Nc;  // multiple of 128
    kgemm1<<<dim3(64 * (cur / 128)), dim3(256), 0, stream>>>(
        embB + (size_t)noff * 512, W0T, smallB, h0, cur);
    kgemm2<<<dim3(64 * (cur / 128)), dim3(256), 0, stream>>>(
        h0, W1T, smallB, pacc, cur);
    kfin<<<dim3((cur * 16 + 255) / 256), dim3(256), 0, stream>>>(
        pacc, smallB, out + (size_t)noff * 16, cur);
  }
}